// Round 1
// baseline (451.759 us; speedup 1.0000x reference)
//
#include <hip/hip_runtime.h>
#include <hip/hip_bf16.h>

typedef __bf16 bf16;
typedef __bf16 bf16x8 __attribute__((ext_vector_type(8)));
typedef float floatx4 __attribute__((ext_vector_type(4)));

#define MFMA16(a, b, c) __builtin_amdgcn_mfma_f32_16x16x32_bf16((a), (b), (c), 0, 0, 0)

__device__ inline void gload_lds16(const void* g, void* l) {
    __builtin_amdgcn_global_load_lds((__attribute__((address_space(1))) void*)g,
                                     (__attribute__((address_space(3))) void*)l, 16, 0, 0);
}

// ---------------------------------------------------------------------------
// Kernel 1: transpose fp32 [R,C] -> bf16 [C,R]
// ---------------------------------------------------------------------------
__global__ __launch_bounds__(256) void transpose_to_bf16(
    const float* __restrict__ in, bf16* __restrict__ out, int R, int C)
{
    __shared__ float tile[64][65];
    int t = threadIdx.x;
    int r0 = blockIdx.y * 64, c0 = blockIdx.x * 64;
    int cl = t & 63, rl = t >> 6;  // 4 rows per pass
#pragma unroll
    for (int i = 0; i < 16; i++)
        tile[rl + i * 4][cl] = in[(size_t)(r0 + rl + i * 4) * C + c0 + cl];
    __syncthreads();
#pragma unroll
    for (int i = 0; i < 16; i++)
        out[(size_t)(c0 + rl + i * 4) * R + r0 + cl] = (bf16)tile[cl][rl + i * 4];
}

// ---------------------------------------------------------------------------
// Kernel 2: h = silu(Y @ W1 + b1), bf16 out.  Y:[B,64] W1:[64,4096]
// block: 256 threads = 256 n-values; each thread does 32 batch rows.
// ---------------------------------------------------------------------------
#define BB 32
__global__ __launch_bounds__(256) void mlp1_kernel(
    const float* __restrict__ Y, const float* __restrict__ W1,
    const float* __restrict__ b1, bf16* __restrict__ h)
{
    int n = blockIdx.x * 256 + threadIdx.x;
    int b0 = blockIdx.y * BB;
    float bias = b1[n];
    float acc[BB];
#pragma unroll
    for (int b = 0; b < BB; b++) acc[b] = bias;
    for (int k = 0; k < 64; k++) {
        float wv = W1[k * 4096 + n];
#pragma unroll
        for (int b = 0; b < BB; b++)
            acc[b] = fmaf(Y[(b0 + b) * 64 + k], wv, acc[b]);  // Y load is wave-uniform -> s_load
    }
#pragma unroll
    for (int b = 0; b < BB; b++) {
        float v = acc[b];
        v = v / (1.f + __expf(-v));  // silu
        h[(size_t)(b0 + b) * 4096 + n] = (bf16)v;
    }
}

// ---------------------------------------------------------------------------
// Kernel 3: C = A @ BT^T + bias  (A:[M,K] bf16, BT:[N,K] bf16, C:[M,N] bf16)
// m97 structure: 128x128 tile, BK=32, global_load_lds width 16, 4 waves,
// each wave 4x4 tiles of 16x16x32 MFMA.
// ---------------------------------------------------------------------------
#define GT 128
#define GK 32
__global__ __launch_bounds__(256) void gemm_bt_bias(
    const bf16* __restrict__ A, const bf16* __restrict__ BT,
    const float* __restrict__ bias, bf16* __restrict__ C,
    int M, int N, int K)
{
    __shared__ bf16 sA[GT * GK];
    __shared__ bf16 sB[GT * GK];
    int t = threadIdx.x, w = t >> 6, l = t & 63;
    int m0 = blockIdx.y * GT, n0 = blockIdx.x * GT;
    int lm = l & 15, q8 = (l >> 4) * 8;
    int wr = (w >> 1) * 64, wc = (w & 1) * 64;

    floatx4 acc[4][4] = {};

    for (int k0 = 0; k0 < K; k0 += GK) {
#pragma unroll
        for (int it = 0; it < 2; ++it) {
            int c = w * 64 + it * 256 + l;   // chunk id 0..511
            int row = c >> 2, ko = (c & 3) * 8;
            const bf16* ga = A + (size_t)(m0 + row) * K + k0 + ko;
            const bf16* gb = BT + (size_t)(n0 + row) * K + k0 + ko;
            // wave-uniform LDS base; HW scatters lane i at base + i*16
            gload_lds16(ga, sA + (size_t)(w * 64 + it * 256) * 8);
            gload_lds16(gb, sB + (size_t)(w * 64 + it * 256) * 8);
        }
        __builtin_amdgcn_s_waitcnt(0);
        __syncthreads();

        bf16x8 af[4], bfr[4];
#pragma unroll
        for (int i = 0; i < 4; i++)
            af[i] = *(const bf16x8*)(sA + (wr + i * 16 + lm) * GK + q8);
#pragma unroll
        for (int j = 0; j < 4; j++)
            bfr[j] = *(const bf16x8*)(sB + (wc + j * 16 + lm) * GK + q8);
#pragma unroll
        for (int i = 0; i < 4; i++)
#pragma unroll
            for (int j = 0; j < 4; j++)
                acc[i][j] = MFMA16(af[i], bfr[j], acc[i][j]);
        __syncthreads();
    }

#pragma unroll
    for (int i = 0; i < 4; i++) {
        int r0 = m0 + wr + i * 16 + (l >> 4) * 4;
#pragma unroll
        for (int j = 0; j < 4; j++) {
            int cc = n0 + wc + j * 16 + lm;
            float bb = bias[cc];
#pragma unroll
            for (int r = 0; r < 4; r++)
                C[(size_t)(r0 + r) * N + cc] = (bf16)(acc[i][j][r] + bb);
        }
    }
}

// ---------------------------------------------------------------------------
// Kernel 4: per-sample out = E (W^T X W) E^T, X = pad(x)+diag, E = emb[b]
// Stages (all fragment LDS reads contiguous b128):
//   C1 = X @ W        (A=sX,  B=W  via sWT)   -> sP  = C1^T
//   C2 = W^T @ C1     (A=sWT, B=C1 via sP)    -> sQ  = C2^T (= C2, symmetric)
//   G  = C2 @ E^T     (A=sQ,  B=E^T via sE)   -> sP  = G^T
//   out= E @ G        (A=sE,  B=G  via sP)    -> global fp32
// ---------------------------------------------------------------------------
#define ST 72  // row stride in bf16 elems: 144B = 9*16B (aligned, bank-rotating)
__global__ __launch_bounds__(256) void batched_congruence(
    const float* __restrict__ x,   // [B,48,48]
    const float* __restrict__ W,   // [64,64]
    const bf16* __restrict__ emb,  // [B,4096]
    float* __restrict__ out)       // [B,4096]
{
    __shared__ bf16 sX[64 * ST], sWT[64 * ST], sE[64 * ST], sP[64 * ST], sQ[64 * ST];
    int t = threadIdx.x, w = t >> 6, l = t & 63;
    int b = blockIdx.x;
    int lm = l & 15, q8 = (l >> 4) * 8;
    int r0 = (w >> 1) * 32, c0 = (w & 1) * 32;

    // zero-fill X (64*72*2 bytes = 2304 dwords = 256*9)
    {
        unsigned* sx32 = (unsigned*)sX;
#pragma unroll
        for (int i = 0; i < 9; i++) sx32[t + 256 * i] = 0u;
    }
    __syncthreads();
    // fill X top-left 48x48 from x (576 float4 chunks)
    {
        const float4* xb = (const float4*)(x + (size_t)b * 2304);
        for (int idx = t; idx < 576; idx += 256) {
            float4 v = xb[idx];
            int row = idx / 12, c4 = (idx % 12) * 4;
            bf16* p = sX + row * ST + c4;
            p[0] = (bf16)v.x; p[1] = (bf16)v.y; p[2] = (bf16)v.z; p[3] = (bf16)v.w;
        }
    }
    if (t >= 48 && t < 64) sX[t * ST + t] = (bf16)1.0f;  // padded diagonal
    // WT[n][k] = W[k][n]
#pragma unroll
    for (int i = 0; i < 16; i++) {
        int idx = t + 256 * i;
        int r = idx >> 6, c = idx & 63;
        sWT[c * ST + r] = (bf16)W[idx];
    }
    // E rows (512 x 16B chunks)
    {
        const uint4* ge = (const uint4*)(emb + (size_t)b * 4096);
#pragma unroll
        for (int i = 0; i < 2; i++) {
            int c = t + 256 * i;
            int row = c >> 3, off = (c & 7) * 8;
            *(uint4*)(sE + row * ST + off) = ge[c];
        }
    }
    __syncthreads();

    // generic 64x64 matmul: both A,B frags are row-contiguous reads
    auto mm = [&](const bf16* PA, const bf16* PB, floatx4 acc[2][2]) {
#pragma unroll
        for (int kc = 0; kc < 2; kc++) {
            bf16x8 a0 = *(const bf16x8*)(PA + (r0 + lm) * ST + kc * 32 + q8);
            bf16x8 a1 = *(const bf16x8*)(PA + (r0 + 16 + lm) * ST + kc * 32 + q8);
            bf16x8 b0 = *(const bf16x8*)(PB + (c0 + lm) * ST + kc * 32 + q8);
            bf16x8 b1 = *(const bf16x8*)(PB + (c0 + 16 + lm) * ST + kc * 32 + q8);
            acc[0][0] = MFMA16(a0, b0, acc[0][0]);
            acc[0][1] = MFMA16(a0, b1, acc[0][1]);
            acc[1][0] = MFMA16(a1, b0, acc[1][0]);
            acc[1][1] = MFMA16(a1, b1, acc[1][1]);
        }
    };
    // store D transposed into SOut (4 consecutive rows -> one 8B write)
    auto storeT = [&](floatx4 acc[2][2], bf16* SOut) {
#pragma unroll
        for (int i = 0; i < 2; i++)
#pragma unroll
            for (int j = 0; j < 2; j++) {
                int R = r0 + i * 16 + (l >> 4) * 4;
                int Cc = c0 + j * 16 + lm;
                union { bf16 h4[4]; uint2 u; } pk;
#pragma unroll
                for (int r = 0; r < 4; r++) pk.h4[r] = (bf16)acc[i][j][r];
                *(uint2*)(SOut + Cc * ST + R) = pk.u;
            }
    };

    floatx4 z = {0.f, 0.f, 0.f, 0.f};
    {   // C1 = X @ W -> sP = C1^T
        floatx4 acc[2][2] = {{z, z}, {z, z}};
        mm(sX, sWT, acc); storeT(acc, sP);
    }
    __syncthreads();
    {   // C2 = W^T @ C1 -> sQ = C2^T
        floatx4 acc[2][2] = {{z, z}, {z, z}};
        mm(sWT, sP, acc); storeT(acc, sQ);
    }
    __syncthreads();
    {   // G = C2 @ E^T -> sP = G^T
        floatx4 acc[2][2] = {{z, z}, {z, z}};
        mm(sQ, sE, acc); storeT(acc, sP);
    }
    __syncthreads();
    {   // out = E @ G -> global fp32
        floatx4 acc[2][2] = {{z, z}, {z, z}};
        mm(sE, sP, acc);
        float* ob = out + (size_t)b * 4096;
#pragma unroll
        for (int i = 0; i < 2; i++)
#pragma unroll
            for (int j = 0; j < 2; j++) {
                int R = r0 + i * 16 + (l >> 4) * 4;
                int Cc = c0 + j * 16 + lm;
#pragma unroll
                for (int r = 0; r < 4; r++)
                    ob[(size_t)(R + r) * 64 + Cc] = acc[i][j][r];
            }
    }
}

// ---------------------------------------------------------------------------
extern "C" void kernel_launch(void* const* d_in, const int* in_sizes, int n_in,
                              void* d_out, int out_size, void* d_ws, size_t ws_size,
                              hipStream_t stream) {
    const float* x  = (const float*)d_in[0];
    // d_in[1] = t (unused by reference)
    const float* Y  = (const float*)d_in[2];
    const float* W  = (const float*)d_in[3];
    const float* W1 = (const float*)d_in[4];
    const float* b1 = (const float*)d_in[5];
    const float* W2 = (const float*)d_in[6];
    const float* b2 = (const float*)d_in[7];
    float* out = (float*)d_out;

    const size_t NN = (size_t)4096 * 4096;
    bf16* h   = (bf16*)d_ws;   // 32 MB
    bf16* W2T = h + NN;        // 32 MB
    bf16* emb = W2T + NN;      // 32 MB

    transpose_to_bf16<<<dim3(64, 64), 256, 0, stream>>>(W2, W2T, 4096, 4096);
    mlp1_kernel<<<dim3(16, 128), 256, 0, stream>>>(Y, W1, b1, h);
    gemm_bt_bias<<<dim3(32, 32), 256, 0, stream>>>(h, W2T, b2, emb, 4096, 4096, 4096);
    batched_congruence<<<4096, 256, 0, stream>>>(x, W, emb, out);
}

// Round 2
// 387.257 us; speedup vs baseline: 1.1666x; 1.1666x over previous
//
#include <hip/hip_runtime.h>
#include <hip/hip_bf16.h>

typedef __bf16 bf16;
typedef __bf16 bf16x8 __attribute__((ext_vector_type(8)));
typedef float floatx4 __attribute__((ext_vector_type(4)));

#define MFMA16(a, b, c) __builtin_amdgcn_mfma_f32_16x16x32_bf16((a), (b), (c), 0, 0, 0)

__device__ inline void gload_lds16(const void* g, void* l) {
    __builtin_amdgcn_global_load_lds((__attribute__((address_space(1))) void*)g,
                                     (__attribute__((address_space(3))) void*)l, 16, 0, 0);
}

// ---------------------------------------------------------------------------
// Kernel 1: transpose fp32 [R,C] -> bf16 [C,R]
// ---------------------------------------------------------------------------
__global__ __launch_bounds__(256) void transpose_to_bf16(
    const float* __restrict__ in, bf16* __restrict__ out, int R, int C)
{
    __shared__ float tile[64][65];
    int t = threadIdx.x;
    int r0 = blockIdx.y * 64, c0 = blockIdx.x * 64;
    int cl = t & 63, rl = t >> 6;
#pragma unroll
    for (int i = 0; i < 16; i++)
        tile[rl + i * 4][cl] = in[(size_t)(r0 + rl + i * 4) * C + c0 + cl];
    __syncthreads();
#pragma unroll
    for (int i = 0; i < 16; i++)
        out[(size_t)(c0 + rl + i * 4) * R + r0 + cl] = (bf16)tile[cl][rl + i * 4];
}

// ---------------------------------------------------------------------------
// Kernel 2: h = silu(Y @ W1 + b1), bf16 out.  Y:[B,64] W1:[64,4096]
// ---------------------------------------------------------------------------
#define BB 32
__global__ __launch_bounds__(256) void mlp1_kernel(
    const float* __restrict__ Y, const float* __restrict__ W1,
    const float* __restrict__ b1, bf16* __restrict__ h)
{
    int n = blockIdx.x * 256 + threadIdx.x;
    int b0 = blockIdx.y * BB;
    float bias = b1[n];
    float acc[BB];
#pragma unroll
    for (int b = 0; b < BB; b++) acc[b] = bias;
    for (int k = 0; k < 64; k++) {
        float wv = W1[k * 4096 + n];
#pragma unroll
        for (int b = 0; b < BB; b++)
            acc[b] = fmaf(Y[(b0 + b) * 64 + k], wv, acc[b]);
    }
#pragma unroll
    for (int b = 0; b < BB; b++) {
        float v = acc[b];
        v = v / (1.f + __expf(-v));
        h[(size_t)(b0 + b) * 4096 + n] = (bf16)v;
    }
}

// ---------------------------------------------------------------------------
// Kernel 3: C = A @ BT^T + bias, 128x128 tile, BK=32.
// Double-buffered LDS, ONE barrier per K-iter: prefetch for k+1 issued at
// top of iter, overlaps compute on k; barrier's vmcnt(0) drain lands after
// a full compute phase. __launch_bounds__(256,4): <=128 unified regs ->
// 4 blocks/CU -> all 1024 blocks resident in one round (no tail).
// XCD swizzle: bid%8 = XCD (dispatch heuristic); each XCD owns 4 tile-rows
// (A slab = 4MB = one L2), sweeping all 32 tile-cols.
// ---------------------------------------------------------------------------
#define GT 128
#define GK 32
__global__ __launch_bounds__(256, 4) void gemm_bt_bias(
    const bf16* __restrict__ A, const bf16* __restrict__ BT,
    const float* __restrict__ bias, bf16* __restrict__ C,
    int M, int N, int K)
{
    __shared__ bf16 sA[2][GT * GK];
    __shared__ bf16 sB[2][GT * GK];
    int t = threadIdx.x, w = t >> 6, l = t & 63;

    int bid = blockIdx.x;
    int xcd = bid & 7, local = bid >> 3;
    int mt = xcd * 4 + (local & 3);
    int nt = local >> 2;
    int m0 = mt * GT, n0 = nt * GT;

    int lm = l & 15, q8 = (l >> 4) * 8;
    int wr = (w >> 1) * 64, wc = (w & 1) * 64;

    // per-lane global src: chunk c = w*64 + it*256 + l -> row = it*64 + rowA,
    // ko = (l&3)*8 (w*64, it*256 are multiples of 4)
    int rowA = (w * 64 + l) >> 2, ko = (l & 3) * 8;
    const bf16* pa = A + (size_t)(m0 + rowA) * K + ko;
    const bf16* pb = BT + (size_t)(n0 + rowA) * K + ko;
    // wave-uniform LDS chunk bases
    const int base0 = (w * 64) * 8, base1 = (w * 64 + 256) * 8;

    floatx4 acc[4][4] = {};

    auto issue = [&](int buf, const bf16* a, const bf16* b) {
        gload_lds16(a, &sA[buf][base0]);
        gload_lds16(a + (size_t)64 * K, &sA[buf][base1]);
        gload_lds16(b, &sB[buf][base0]);
        gload_lds16(b + (size_t)64 * K, &sB[buf][base1]);
    };

    const int KT = K / GK;
    issue(0, pa, pb);
    pa += GK; pb += GK;
    __syncthreads();  // drains vmcnt -> buf0 ready

    for (int kt = 0; kt < KT; ++kt) {
        int cur = kt & 1;
        if (kt + 1 < KT) {
            issue(cur ^ 1, pa, pb);  // in flight during compute below
            pa += GK; pb += GK;
        }
        const bf16* LA = sA[cur];
        const bf16* LB = sB[cur];
        bf16x8 af[4], bfr[4];
#pragma unroll
        for (int i = 0; i < 4; i++)
            af[i] = *(const bf16x8*)(LA + (wr + i * 16 + lm) * GK + q8);
#pragma unroll
        for (int j = 0; j < 4; j++)
            bfr[j] = *(const bf16x8*)(LB + (wc + j * 16 + lm) * GK + q8);
#pragma unroll
        for (int i = 0; i < 4; i++)
#pragma unroll
            for (int j = 0; j < 4; j++)
                acc[i][j] = MFMA16(af[i], bfr[j], acc[i][j]);
        __syncthreads();  // drains prefetch (overlapped) + protects cur reuse
    }

#pragma unroll
    for (int i = 0; i < 4; i++) {
        int r0 = m0 + wr + i * 16 + (l >> 4) * 4;
#pragma unroll
        for (int j = 0; j < 4; j++) {
            int cc = n0 + wc + j * 16 + lm;
            float bb = bias[cc];
#pragma unroll
            for (int r = 0; r < 4; r++)
                C[(size_t)(r0 + r) * N + cc] = (bf16)(acc[i][j][r] + bb);
        }
    }
}

// ---------------------------------------------------------------------------
// Kernel 4: out = E (W^T X W) E^T = F X F^T with F = E W^T (X symmetric).
// mm(PA,PB) computes C = PA . PB^T with row-contiguous b128 reads of both.
//   S1: F  = mm(sE, sW)  -> storeN sP   (x global loads overlap S1 MFMA)
//   S2: T1 = mm(sP, sX)  -> storeN sE   (T1 = F.X = F.X^T, X symmetric)
//   S3: out= mm(sE, sP)  -> global      (out = T1.F^T)
// 4 LDS buffers (36.8 KB) -> 4 blocks/CU.
// ---------------------------------------------------------------------------
#define ST 72
__global__ __launch_bounds__(256) void batched_congruence(
    const float* __restrict__ x,   // [B,48,48]
    const float* __restrict__ W,   // [64,64]
    const bf16* __restrict__ emb,  // [B,4096]
    float* __restrict__ out)       // [B,4096]
{
    __shared__ bf16 sX[64 * ST], sW[64 * ST], sE[64 * ST], sP[64 * ST];
    int t = threadIdx.x, w = t >> 6, l = t & 63;
    int b = blockIdx.x;
    int lm = l & 15, q8 = (l >> 4) * 8;
    int r0 = (w >> 1) * 32, c0 = (w & 1) * 32;

    // phase A: zero sX; load W rows; load E rows
    {
        unsigned* sx32 = (unsigned*)sX;
#pragma unroll
        for (int i = 0; i < 9; i++) sx32[t + 256 * i] = 0u;
    }
#pragma unroll
    for (int i = 0; i < 16; i++) {
        int idx = t + 256 * i;
        sW[(idx >> 6) * ST + (idx & 63)] = (bf16)W[idx];
    }
    {
        const uint4* ge = (const uint4*)(emb + (size_t)b * 4096);
#pragma unroll
        for (int i = 0; i < 2; i++) {
            int c = t + 256 * i;
            *(uint4*)(sE + (c >> 3) * ST + (c & 7) * 8) = ge[c];
        }
    }
    __syncthreads();

    auto mm = [&](const bf16* PA, const bf16* PB, floatx4 acc[2][2]) {
#pragma unroll
        for (int kc = 0; kc < 2; kc++) {
            bf16x8 a0 = *(const bf16x8*)(PA + (r0 + lm) * ST + kc * 32 + q8);
            bf16x8 a1 = *(const bf16x8*)(PA + (r0 + 16 + lm) * ST + kc * 32 + q8);
            bf16x8 b0 = *(const bf16x8*)(PB + (c0 + lm) * ST + kc * 32 + q8);
            bf16x8 b1 = *(const bf16x8*)(PB + (c0 + 16 + lm) * ST + kc * 32 + q8);
            acc[0][0] = MFMA16(a0, b0, acc[0][0]);
            acc[0][1] = MFMA16(a0, b1, acc[0][1]);
            acc[1][0] = MFMA16(a1, b0, acc[1][0]);
            acc[1][1] = MFMA16(a1, b1, acc[1][1]);
        }
    };
    auto storeN = [&](floatx4 acc[2][2], bf16* SOut) {
#pragma unroll
        for (int i = 0; i < 2; i++)
#pragma unroll
            for (int j = 0; j < 2; j++) {
                int R = r0 + i * 16 + (l >> 4) * 4;
                int Cc = c0 + j * 16 + lm;
#pragma unroll
                for (int r = 0; r < 4; r++)
                    SOut[(R + r) * ST + Cc] = (bf16)acc[i][j][r];
            }
    };

    floatx4 z = {0.f, 0.f, 0.f, 0.f};

    // phase B: issue x loads (regs), run S1 under the load latency, then fill sX
    {
        const float4* xb = (const float4*)(x + (size_t)b * 2304);
        float4 v0 = xb[t];
        float4 v1 = xb[t + 256];
        float4 v2 = (t < 64) ? xb[t + 512] : make_float4(0.f, 0.f, 0.f, 0.f);

        floatx4 acc[2][2] = {{z, z}, {z, z}};
        mm(sE, sW, acc);  // S1: F = E . W^T

        // fill X top-left 48x48 (576 float4 chunks; 12 chunks per 48-col row)
        {
            int idx = t;
            bf16* p = sX + (idx / 12) * ST + (idx % 12) * 4;
            p[0] = (bf16)v0.x; p[1] = (bf16)v0.y; p[2] = (bf16)v0.z; p[3] = (bf16)v0.w;
            idx = t + 256;
            p = sX + (idx / 12) * ST + (idx % 12) * 4;
            p[0] = (bf16)v1.x; p[1] = (bf16)v1.y; p[2] = (bf16)v1.z; p[3] = (bf16)v1.w;
            if (t < 64) {
                idx = t + 512;
                p = sX + (idx / 12) * ST + (idx % 12) * 4;
                p[0] = (bf16)v2.x; p[1] = (bf16)v2.y; p[2] = (bf16)v2.z; p[3] = (bf16)v2.w;
            }
        }
        if (t >= 48 && t < 64) sX[t * ST + t] = (bf16)1.0f;  // padded diagonal
        storeN(acc, sP);  // F rows
    }
    __syncthreads();

    {   // S2: T1 = F . X^T (= F.X)
        floatx4 acc[2][2] = {{z, z}, {z, z}};
        mm(sP, sX, acc);
        storeN(acc, sE);  // T1 rows (E dead)
    }
    __syncthreads();

    {   // S3: out = T1 . F^T
        floatx4 acc[2][2] = {{z, z}, {z, z}};
        mm(sE, sP, acc);
        float* ob = out + (size_t)b * 4096;
#pragma unroll
        for (int i = 0; i < 2; i++)
#pragma unroll
            for (int j = 0; j < 2; j++) {
                int R = r0 + i * 16 + (l >> 4) * 4;
                int Cc = c0 + j * 16 + lm;
#pragma unroll
                for (int r = 0; r < 4; r++)
                    ob[(size_t)(R + r) * 64 + Cc] = acc[i][j][r];
            }
    }
}

// ---------------------------------------------------------------------------
extern "C" void kernel_launch(void* const* d_in, const int* in_sizes, int n_in,
                              void* d_out, int out_size, void* d_ws, size_t ws_size,
                              hipStream_t stream) {
    const float* x  = (const float*)d_in[0];
    const float* Y  = (const float*)d_in[2];
    const float* W  = (const float*)d_in[3];
    const float* W1 = (const float*)d_in[4];
    const float* b1 = (const float*)d_in[5];
    const float* W2 = (const float*)d_in[6];
    const float* b2 = (const float*)d_in[7];
    float* out = (float*)d_out;

    const size_t NN = (size_t)4096 * 4096;
    bf16* h   = (bf16*)d_ws;
    bf16* W2T = h + NN;
    bf16* emb = W2T + NN;

    transpose_to_bf16<<<dim3(64, 64), 256, 0, stream>>>(W2, W2T, 4096, 4096);
    mlp1_kernel<<<dim3(16, 128), 256, 0, stream>>>(Y, W1, b1, h);
    gemm_bt_bias<<<1024, 256, 0, stream>>>(h, W2T, b2, emb, 4096, 4096, 4096);
    batched_congruence<<<4096, 256, 0, stream>>>(x, W, emb, out);
}